// Round 10
// baseline (840.346 us; speedup 1.0000x reference)
//
#include <hip/hip_runtime.h>
#include <cstdint>

typedef unsigned short u16;
typedef unsigned char u8;
typedef __attribute__((ext_vector_type(8))) __bf16 bf16x8;
typedef __attribute__((ext_vector_type(4))) float f32x4;
typedef __attribute__((ext_vector_type(2))) unsigned u32x2;

#define MFMA16(a, b, c) __builtin_amdgcn_mfma_f32_16x16x32_bf16((a), (b), (c), 0, 0, 0)

__device__ __forceinline__ u16 f2b(float f) {            // SW RNE (prep kernels only)
    union { float f; unsigned u; } v; v.f = f;
    unsigned r = v.u + 0x7fffu + ((v.u >> 16) & 1u);
    return (u16)(r >> 16);
}
__device__ __forceinline__ u16 f2b_hw(float f) {         // HW cvt (hot path)
    union { __bf16 h; u16 u; } cv; cv.h = (__bf16)f; return cv.u;
}
__device__ __forceinline__ float b2f(u16 h) {
    union { unsigned u; float f; } v; v.u = ((unsigned)h) << 16; return v.f;
}
// HW packed cvt: 2 f32 -> 1 dword of 2 bf16 (RNE, same rounding as __bf16 cast).
__device__ __forceinline__ unsigned cvt_pk_bf16(float lo, float hi) {
    unsigned r;
    asm("v_cvt_pk_bf16_f32 %0, %1, %2" : "=v"(r) : "v"(lo), "v"(hi));
    return r;
}
__device__ __forceinline__ float fast_rcp(float x) { return __builtin_amdgcn_rcpf(x); }
// mish(x) = x * tanh(softplus(x)); with s=e^x, tanh(softplus) = s(s+2)/(s(s+2)+2)
__device__ __forceinline__ float mish_f(float x) {
    float s = __expf(fminf(x, 40.0f));
    float p = s * (s + 2.0f);
    return x * p * fast_rcp(p + 2.0f);
}
__device__ __forceinline__ float tanh_f(float y) {
    float e = __expf(2.0f * y);
    return 1.0f - 2.0f * fast_rcp(e + 1.0f);
}
__device__ __forceinline__ float sigmoid_f(float y) {
    return fast_rcp(1.0f + __expf(-y));
}
__device__ __forceinline__ float splus(float w) { return log1pf(__expf(w)); }

// Round history: r3 mfma(W,x): -20us. r4 gate-skip: -20us. r5 prep widening:
// null (prep incompressible). r6 pipelining: null. r7 128-row tile: spill.
// r9 LDS 39936->35840 + setprio: k_main 195->188 (BEST), occupancy unmoved.
// Block wall-lifetime ~42us vs ~13us/SIMD issue work => ~70% simultaneous
// all-wave stall. Round-10 is a PAID DIAGNOSTIC: two ablated clones run
// before the real k_main (which is byte-identical to r9): k_abl<2> = no
// in-loop global B-fragment loads (fixed register B); k_abl<3> = no
// inter-phase barriers (racy, garbage values, perf-valid). Both at 2 reps so
// they exceed k_main and surface in the top-5 with counters. out is never
// written by ablations; values kept live via asm keep-alives (DCE rule).

template <int CTRL>
__device__ __forceinline__ float dpp_add(float v) {
    union { float f; int i; } s, p;
    s.f = v;
    p.i = __builtin_amdgcn_update_dpp(0, s.i, CTRL, 0xf, 0xf, true);
    return v + p.f;
}

// ---------------- workspace layout (bytes) ----------------
#define WS_PERM      0u           // int[18*16384] = 294912 slots
#define WS_CNT       1179648u     // int, 18 counters at stride 32 ints (128 B lines)
#define WS_SP        1183744u     // float[32]
#define WS_W1P       1184768u     // u16[512*32]   [n][k]
#define WS_W2F       1217536u     // u16[256*512]  fragment-major NT=16 KB=16
#define WS_HW1F      1479680u     // u16[9*128*256] fragment-major per band NT=8 KB=8
#define WS_SWF       2069504u     // u16[64*256]   fragment-major NT=4 KB=8
#define WS_STWF      2102272u     // u16[64*256]
#define WS_NEEDED    2135040u

#define GFLAG_IDX    600          // int index into cnt area

#define NSUB         2            // sub-regions per band
#define CAPH         16384        // rows per sub-region (E~14563, 15 sigma)
#define REG_BLOCKS   256          // k_main blocks per sub-region = CAPH/64

// ---------------- fused prep: weight packing + atomic counting-sort scatter ----
__global__ __launch_bounds__(512) void k_pack(const float* __restrict__ x, int B,
                       const float* __restrict__ tw1, const float* __restrict__ tw2,
                       const float* __restrict__ hw1,
                       const float* __restrict__ sw1, const float* __restrict__ stw1,
                       const float* __restrict__ sw2, const float* __restrict__ stw2,
                       const float* __restrict__ sun_w1, const float* __restrict__ sun_w2,
                       const float* __restrict__ storm_w1, const float* __restrict__ storm_w2,
                       u16* __restrict__ W1p, u16* __restrict__ W2f, u16* __restrict__ HWf,
                       u16* __restrict__ SWf, u16* __restrict__ STWf,
                       float* __restrict__ sp, int* __restrict__ cnt,
                       int* __restrict__ perm)
{
    __shared__ int wcnt[8][9];
    __shared__ int wpre[8][9];
    __shared__ int bbase[9];
    __shared__ u8 bL[512];
    const int tid  = threadIdx.x;
    const int lane = tid & 63, wave = tid >> 6;
    const int sub  = blockIdx.x & (NSUB - 1);  // parity sub-region
    const int i    = blockIdx.x * 512 + tid;

    {
        const size_t ebase = (size_t)blockIdx.x * 512 * 18;
        const float2* xs = (const float2*)(x + ebase);
        const size_t etotal = (size_t)B * 18;
        for (int p = tid; p < 4608; p += 512) {
            if (ebase + (size_t)p * 2 + 1 < etotal) {
                float2 v = xs[p];
                int e0 = p * 2;
                int r0 = e0 / 18, c0 = e0 - r0 * 18;   // c0 always even
                if (c0 == 16) bL[r0] = (u8)(int)v.y;   // element 17 = band
            }
        }
    }
    __syncthreads();

    int band = -1, rank = 0;
    if (i < B) band = (int)bL[tid];
    for (int k = 0; k < 9; ++k) {
        unsigned long long m = __ballot(band == k);
        if (band == k) rank = __popcll(m & ((1ull << lane) - 1ull));
        if (lane == 0) wcnt[wave][k] = __popcll(m);
    }
    __syncthreads();
    if (tid < 9) {
        int run = 0;
        for (int w = 0; w < 8; ++w) { wpre[w][tid] = run; run += wcnt[w][tid]; }
        bbase[tid] = atomicAdd(&cnt[(tid * NSUB + sub) * 32], run);
    }
    __syncthreads();
    if (band >= 0)
        perm[(band * NSUB + sub) * CAPH + bbase[band] + wpre[wave][band] + rank] = i;

    if (blockIdx.x == 0 && tid < 64) {
        bool z = (sw2[tid] == 0.0f) && (stw2[tid] == 0.0f);
        unsigned long long m = __ballot(z);
        if (tid == 0) cnt[GFLAG_IDX] = (m == ~0ull) ? 1 : 0;
    }

    const int gtid = blockIdx.x * 512 + tid;
    if (gtid < 32) {
        const float* srcs[4] = { sun_w1, sun_w2, storm_w1, storm_w2 };
        float w = srcs[gtid >> 3][gtid & 7];
        sp[gtid] = splus(w);
    }
    const int total = 16384 + 131072 + 294912 + 16384 + 16384;
    for (int i2 = gtid; i2 < total; i2 += 512 * 512) {
        int idx = i2;
        if (idx < 16384) {                         // W1p[n][k] : 512 x 32 (k>=15 zero)
            int n = idx >> 5, k = idx & 31;
            W1p[idx] = (k < 15) ? f2b(tw1[k * 512 + n]) : (u16)0;
        } else if ((idx -= 16384) < 131072) {      // W2f: FM NT=16 KB=16
            int tile = idx >> 9, within = idx & 511;
            int lane2 = within >> 3, j = within & 7;
            int nt = tile >> 4, kb = tile & 15;
            int n = nt * 16 + (lane2 & 15);
            int k = kb * 32 + (lane2 >> 4) * 8 + j;
            W2f[idx] = f2b(tw2[k * 256 + n]);
        } else if ((idx -= 131072) < 294912) {     // HWf: per band g, FM NT=8 KB=8
            int g = idx >> 15, r = idx & 32767;
            int tile = r >> 9, within = r & 511;
            int lane2 = within >> 3, j = within & 7;
            int nt = tile >> 3, kb = tile & 7;
            int n = nt * 16 + (lane2 & 15);
            int k = kb * 32 + (lane2 >> 4) * 8 + j;
            HWf[idx] = f2b(hw1[(g * 256 + k) * 128 + n]);
        } else if ((idx -= 294912) < 16384) {      // SWf: FM NT=4 KB=8
            int tile = idx >> 9, within = idx & 511;
            int lane2 = within >> 3, j = within & 7;
            int nt = tile >> 3, kb = tile & 7;
            int n = nt * 16 + (lane2 & 15);
            int k = kb * 32 + (lane2 >> 4) * 8 + j;
            SWf[idx] = f2b(sw1[k * 64 + n]);
        } else {                                   // STWf
            idx -= 16384;
            int tile = idx >> 9, within = idx & 511;
            int lane2 = within >> 3, j = within & 7;
            int nt = tile >> 3, kb = tile & 7;
            int n = nt * 16 + (lane2 & 15);
            int k = kb * 32 + (lane2 >> 4) * 8 + j;
            STWf[idx] = f2b(stw1[k * 64 + n]);
        }
    }
}

// ---------------- fused main kernel (r9-identical) ----------------
__global__ __launch_bounds__(512, 4) void k_main(
                       const float* __restrict__ x,
                       const int* __restrict__ perm,
                       const int* __restrict__ cnt,
                       const u16* __restrict__ W1p, const u16* __restrict__ W2f,
                       const u16* __restrict__ HWf,
                       const u16* __restrict__ SWf, const u16* __restrict__ STWf,
                       const float* __restrict__ tb1, const float* __restrict__ tb2,
                       const float* __restrict__ hb1, const float* __restrict__ hw2,
                       const float* __restrict__ hb2,
                       const float* __restrict__ sb1, const float* __restrict__ sw2,
                       const float* __restrict__ sb2,
                       const float* __restrict__ stb1, const float* __restrict__ stw2,
                       const float* __restrict__ stb2,
                       const float* __restrict__ sp,
                       const float* __restrict__ sun_b1, const float* __restrict__ sun_b2,
                       const float* __restrict__ storm_b1, const float* __restrict__ storm_b2,
                       float* __restrict__ out)
{
    const int region = blockIdx.x >> 8;        // 0..17
    const int loc    = blockIdx.x & 255;
    const int bb     = region >> 1;            // band
    const int nr0    = cnt[region * 32] - loc * 64;
    if (nr0 <= 0) return;
    const int nrows  = nr0 > 64 ? 64 : nr0;
    const int rstart = region * CAPH + loc * 64;
    const int gskip  = cnt[GFLAG_IDX];         // 1 -> gate GEMMs are exactly 0

    __shared__ __align__(16) u16 bufmem[2][64][136];   // 34,816 B
    __shared__ int rowsL[64];
    __shared__ float sfiL[64], kpL[64];
    u16 (*xA)[32]  = (u16(*)[32])&bufmem[1][0][0];
    float (*red)[64] = (float(*)[64])&bufmem[0][0][0];

    int tid = threadIdx.x;
    int lane = tid & 63, wave = tid >> 6;      // wave 0..7
    int quad = lane >> 4, l15 = lane & 15;

    if (tid < 64) {
        int r = rstart + (tid < nrows ? tid : 0);
        rowsL[tid] = perm[r];
    }
    for (int i = tid; i < 64 * 16; i += 512) ((unsigned*)&xA[0][0])[i] = 0u;
    __syncthreads();
    for (int i = tid; i < 64 * 18; i += 512) {
        int r = i / 18, c = i - r * 18;
        float v = x[rowsL[r] * 18 + c];
        if (c < 15) xA[r][c] = f2b_hw(v);
        else if (c == 15) sfiL[r] = v;
        else if (c == 16) kpL[r] = v;
    }
    __syncthreads();

    bf16x8 ax[4];
#pragma unroll
    for (int mt = 0; mt < 4; ++mt)
        ax[mt] = *(const bf16x8*)&xA[mt * 16 + l15][quad * 8];

    const int colq = wave * 16 + quad * 4;

    f32x4 acc2[2][4];
#pragma unroll
    for (int ntl = 0; ntl < 2; ++ntl) {
        const f32x4 b2v = *(const f32x4*)&tb2[wave * 32 + ntl * 16 + quad * 4];
#pragma unroll
        for (int mt = 0; mt < 4; ++mt) acc2[ntl][mt] = b2v;
    }

    for (int c = 0; c < 4; ++c) {
        f32x4 acc1[4];
        {
            const f32x4 b1v = *(const f32x4*)&tb1[c * 128 + colq];
            bf16x8 bw = *(const bf16x8*)&W1p[(c * 128 + wave * 16 + l15) * 32 + quad * 8];
#pragma unroll
            for (int mt = 0; mt < 4; ++mt) { acc1[mt] = b1v; acc1[mt] = MFMA16(bw, ax[mt], acc1[mt]); }
        }
        u16 (*bufc)[136] = bufmem[c & 1];
#pragma unroll
        for (int mt = 0; mt < 4; ++mt) {
            u32x2 pk;
            pk.x = cvt_pk_bf16(mish_f(acc1[mt][0]), mish_f(acc1[mt][1]));
            pk.y = cvt_pk_bf16(mish_f(acc1[mt][2]), mish_f(acc1[mt][3]));
            *(u32x2*)&bufc[mt * 16 + l15][colq] = pk;
        }
        __syncthreads();
        for (int ks = 0; ks < 4; ++ks) {
            bf16x8 a2[4];
#pragma unroll
            for (int mt = 0; mt < 4; ++mt)
                a2[mt] = *(const bf16x8*)&bufc[mt * 16 + l15][ks * 32 + quad * 8];
            int kb = c * 4 + ks;
            __builtin_amdgcn_s_setprio(1);
#pragma unroll
            for (int ntl = 0; ntl < 2; ++ntl) {
                int nt = wave * 2 + ntl;
                bf16x8 bw = *(const bf16x8*)&W2f[((nt * 16 + kb) << 9) + lane * 8];
#pragma unroll
                for (int mt = 0; mt < 4; ++mt)
                    acc2[ntl][mt] = MFMA16(bw, a2[mt], acc2[ntl][mt]);
            }
            __builtin_amdgcn_s_setprio(0);
        }
    }
    __syncthreads();

    u16 (*tmat)[264] = (u16(*)[264])bufmem;
#pragma unroll
    for (int ntl = 0; ntl < 2; ++ntl) {
        const int colb = wave * 32 + ntl * 16 + quad * 4;
#pragma unroll
        for (int mt = 0; mt < 4; ++mt) {
            u32x2 pk;
            pk.x = cvt_pk_bf16(mish_f(acc2[ntl][mt][0]), mish_f(acc2[ntl][mt][1]));
            pk.y = cvt_pk_bf16(mish_f(acc2[ntl][mt][2]), mish_f(acc2[ntl][mt][3]));
            *(u32x2*)&tmat[mt * 16 + l15][colb] = pk;
        }
    }
    __syncthreads();

    const u16* Hw = HWf + bb * 32768;
    const u16* Gw = (wave < 4) ? SWf : STWf;
    int gnt = wave & 3;
    f32x4 acch[4], accg[4];
    {
        const f32x4 hb = *(const f32x4*)&hb1[bb * 128 + colq];
#pragma unroll
        for (int mt = 0; mt < 4; ++mt) acch[mt] = hb;
    }
    if (!gskip) {
        const int nb = gnt * 16 + quad * 4;
        const f32x4 gb = (wave < 4) ? *(const f32x4*)&sb1[nb] : *(const f32x4*)&stb1[nb];
#pragma unroll
        for (int mt = 0; mt < 4; ++mt) accg[mt] = gb;
    }
    for (int kb = 0; kb < 8; ++kb) {
        bf16x8 a3[4];
#pragma unroll
        for (int mt = 0; mt < 4; ++mt)
            a3[mt] = *(const bf16x8*)&tmat[mt * 16 + l15][kb * 32 + quad * 8];
        bf16x8 bh = *(const bf16x8*)&Hw[((wave * 8 + kb) << 9) + lane * 8];
        __builtin_amdgcn_s_setprio(1);
#pragma unroll
        for (int mt = 0; mt < 4; ++mt)
            acch[mt] = MFMA16(bh, a3[mt], acch[mt]);
        if (!gskip) {
            bf16x8 bg = *(const bf16x8*)&Gw[((gnt * 8 + kb) << 9) + lane * 8];
#pragma unroll
            for (int mt = 0; mt < 4; ++mt)
                accg[mt] = MFMA16(bg, a3[mt], accg[mt]);
        }
        __builtin_amdgcn_s_setprio(0);
    }
    __syncthreads();

    {
        const f32x4 wv = *(const f32x4*)&hw2[bb * 128 + colq];
#pragma unroll
        for (int mt = 0; mt < 4; ++mt) {
            float s = mish_f(acch[mt][0]) * wv[0];
            s += mish_f(acch[mt][1]) * wv[1];
            s += mish_f(acch[mt][2]) * wv[2];
            s += mish_f(acch[mt][3]) * wv[3];
            s += __shfl_xor(s, 16); s += __shfl_xor(s, 32);
            if (quad == 0) red[wave][mt * 16 + l15] = s;
        }
    }
    if (!gskip) {
        const int nb = gnt * 16 + quad * 4;
        const f32x4 gw = (wave < 4) ? *(const f32x4*)&sw2[nb] : *(const f32x4*)&stw2[nb];
#pragma unroll
        for (int mt = 0; mt < 4; ++mt) {
            float s = mish_f(accg[mt][0]) * gw[0];
            s += mish_f(accg[mt][1]) * gw[1];
            s += mish_f(accg[mt][2]) * gw[2];
            s += mish_f(accg[mt][3]) * gw[3];
            s += __shfl_xor(s, 16); s += __shfl_xor(s, 32);
            if (quad == 0) red[8 + wave][mt * 16 + l15] = s;
        }
    }
    __syncthreads();

    if (tid < 64 && tid < nrows) {
        int row = tid;
        float head = hb2[bb];
#pragma unroll
        for (int w = 0; w < 8; ++w) head += red[w][row];
        float sl = sb2[0], tl = stb2[0];
        if (!gskip) {
#pragma unroll
            for (int w = 0; w < 4; ++w) { sl += red[8 + w][row]; tl += red[12 + w][row]; }
        }
        float sg = sigmoid_f(sl);
        float tg = sigmoid_f(tl);
        float v1 = sfiL[row], v2 = kpL[row];
        float sun_val = sun_b2[0], storm_val = storm_b2[0];
#pragma unroll
        for (int j = 0; j < 8; ++j) {
            sun_val   += tanh_f(v1 * sp[j]      + sun_b1[j])   * sp[8 + j];
            storm_val += tanh_f(v2 * sp[16 + j] + storm_b1[j]) * sp[24 + j];
        }
        out[rowsL[row]] = head + sg * sun_val + tg * storm_val;
    }
}

// ---------------- diagnostic ablation clones (write NOTHING to out) ----------
// V==2: no in-loop global B-fragment loads (fixed register B operand).
// V==3: no inter-phase barriers (racy LDS, garbage values, perf-valid).
// Both run the compute body twice (REPS=2) so their dispatch duration exceeds
// k_main's and they surface in the rocprof top-5 with their own counters.
template <int V>
__global__ __launch_bounds__(512, 4) void k_abl(
                       const float* __restrict__ x,
                       const int* __restrict__ perm,
                       const int* __restrict__ cnt,
                       const u16* __restrict__ W1p, const u16* __restrict__ W2f,
                       const u16* __restrict__ HWf,
                       const u16* __restrict__ SWf, const u16* __restrict__ STWf,
                       const float* __restrict__ tb1, const float* __restrict__ tb2,
                       const float* __restrict__ hb1, const float* __restrict__ hw2,
                       const float* __restrict__ hb2,
                       const float* __restrict__ sb1, const float* __restrict__ sw2,
                       const float* __restrict__ sb2,
                       const float* __restrict__ stb1, const float* __restrict__ stw2,
                       const float* __restrict__ stb2,
                       const float* __restrict__ sp,
                       const float* __restrict__ sun_b1, const float* __restrict__ sun_b2,
                       const float* __restrict__ storm_b1, const float* __restrict__ storm_b2,
                       float* __restrict__ out)
{
    (void)out;
    const int region = blockIdx.x >> 8;
    const int loc    = blockIdx.x & 255;
    const int bb     = region >> 1;
    const int nr0    = cnt[region * 32] - loc * 64;
    if (nr0 <= 0) return;
    const int nrows  = nr0 > 64 ? 64 : nr0;
    const int rstart = region * CAPH + loc * 64;
    const int gskip  = cnt[GFLAG_IDX];

    __shared__ __align__(16) u16 bufmem[2][64][136];
    __shared__ int rowsL[64];
    __shared__ float sfiL[64], kpL[64];
    u16 (*xA)[32]  = (u16(*)[32])&bufmem[1][0][0];
    float (*red)[64] = (float(*)[64])&bufmem[0][0][0];

    int tid = threadIdx.x;
    int lane = tid & 63, wave = tid >> 6;
    int quad = lane >> 4, l15 = lane & 15;

    if (tid < 64) {
        int r = rstart + (tid < nrows ? tid : 0);
        rowsL[tid] = perm[r];
    }
    for (int i = tid; i < 64 * 16; i += 512) ((unsigned*)&xA[0][0])[i] = 0u;
    __syncthreads();
    for (int i = tid; i < 64 * 18; i += 512) {
        int r = i / 18, c = i - r * 18;
        float v = x[rowsL[r] * 18 + c];
        if (c < 15) xA[r][c] = f2b_hw(v);
        else if (c == 15) sfiL[r] = v;
        else if (c == 16) kpL[r] = v;
    }
    __syncthreads();

    const bf16x8 bfix = *(const bf16x8*)&W2f[lane * 8];   // fixed B for V==2
    const int colq = wave * 16 + quad * 4;

    for (int rep = 0; rep < 2; ++rep) {
        bf16x8 ax[4];
#pragma unroll
        for (int mt = 0; mt < 4; ++mt)
            ax[mt] = *(const bf16x8*)&xA[mt * 16 + l15][quad * 8];

        f32x4 acc2[2][4];
#pragma unroll
        for (int ntl = 0; ntl < 2; ++ntl) {
            const f32x4 b2v = *(const f32x4*)&tb2[wave * 32 + ntl * 16 + quad * 4];
#pragma unroll
            for (int mt = 0; mt < 4; ++mt) acc2[ntl][mt] = b2v;
        }

        for (int c = 0; c < 4; ++c) {
            f32x4 acc1[4];
            {
                const f32x4 b1v = *(const f32x4*)&tb1[c * 128 + colq];
                bf16x8 bw;
                if constexpr (V == 2) bw = bfix;
                else bw = *(const bf16x8*)&W1p[(c * 128 + wave * 16 + l15) * 32 + quad * 8];
#pragma unroll
                for (int mt = 0; mt < 4; ++mt) { acc1[mt] = b1v; acc1[mt] = MFMA16(bw, ax[mt], acc1[mt]); }
            }
            u16 (*bufc)[136] = bufmem[c & 1];
#pragma unroll
            for (int mt = 0; mt < 4; ++mt) {
                u32x2 pk;
                pk.x = cvt_pk_bf16(mish_f(acc1[mt][0]), mish_f(acc1[mt][1]));
                pk.y = cvt_pk_bf16(mish_f(acc1[mt][2]), mish_f(acc1[mt][3]));
                *(u32x2*)&bufc[mt * 16 + l15][colq] = pk;
            }
            if constexpr (V != 3) __syncthreads();
            for (int ks = 0; ks < 4; ++ks) {
                bf16x8 a2[4];
#pragma unroll
                for (int mt = 0; mt < 4; ++mt)
                    a2[mt] = *(const bf16x8*)&bufc[mt * 16 + l15][ks * 32 + quad * 8];
                int kb = c * 4 + ks;
                __builtin_amdgcn_s_setprio(1);
#pragma unroll
                for (int ntl = 0; ntl < 2; ++ntl) {
                    int nt = wave * 2 + ntl;
                    bf16x8 bw;
                    if constexpr (V == 2) bw = bfix;
                    else bw = *(const bf16x8*)&W2f[((nt * 16 + kb) << 9) + lane * 8];
#pragma unroll
                    for (int mt = 0; mt < 4; ++mt)
                        acc2[ntl][mt] = MFMA16(bw, a2[mt], acc2[ntl][mt]);
                }
                __builtin_amdgcn_s_setprio(0);
            }
        }
        if constexpr (V != 3) __syncthreads();

        u16 (*tmat)[264] = (u16(*)[264])bufmem;
#pragma unroll
        for (int ntl = 0; ntl < 2; ++ntl) {
            const int colb = wave * 32 + ntl * 16 + quad * 4;
#pragma unroll
            for (int mt = 0; mt < 4; ++mt) {
                u32x2 pk;
                pk.x = cvt_pk_bf16(mish_f(acc2[ntl][mt][0]), mish_f(acc2[ntl][mt][1]));
                pk.y = cvt_pk_bf16(mish_f(acc2[ntl][mt][2]), mish_f(acc2[ntl][mt][3]));
                *(u32x2*)&tmat[mt * 16 + l15][colb] = pk;
            }
        }
        if constexpr (V != 3) __syncthreads();

        const u16* Hw = HWf + bb * 32768;
        const u16* Gw = (wave < 4) ? SWf : STWf;
        int gnt = wave & 3;
        f32x4 acch[4], accg[4];
        {
            const f32x4 hb = *(const f32x4*)&hb1[bb * 128 + colq];
#pragma unroll
            for (int mt = 0; mt < 4; ++mt) acch[mt] = hb;
        }
        if (!gskip) {
            const int nb = gnt * 16 + quad * 4;
            const f32x4 gb = (wave < 4) ? *(const f32x4*)&sb1[nb] : *(const f32x4*)&stb1[nb];
#pragma unroll
            for (int mt = 0; mt < 4; ++mt) accg[mt] = gb;
        }
        for (int kb = 0; kb < 8; ++kb) {
            bf16x8 a3[4];
#pragma unroll
            for (int mt = 0; mt < 4; ++mt)
                a3[mt] = *(const bf16x8*)&tmat[mt * 16 + l15][kb * 32 + quad * 8];
            bf16x8 bh;
            if constexpr (V == 2) bh = bfix;
            else bh = *(const bf16x8*)&Hw[((wave * 8 + kb) << 9) + lane * 8];
            __builtin_amdgcn_s_setprio(1);
#pragma unroll
            for (int mt = 0; mt < 4; ++mt)
                acch[mt] = MFMA16(bh, a3[mt], acch[mt]);
            if (!gskip) {
                bf16x8 bg;
                if constexpr (V == 2) bg = bfix;
                else bg = *(const bf16x8*)&Gw[((gnt * 8 + kb) << 9) + lane * 8];
#pragma unroll
                for (int mt = 0; mt < 4; ++mt)
                    accg[mt] = MFMA16(bg, a3[mt], accg[mt]);
            }
            __builtin_amdgcn_s_setprio(0);
        }
        if constexpr (V != 3) __syncthreads();

        {
            const f32x4 wv = *(const f32x4*)&hw2[bb * 128 + colq];
#pragma unroll
            for (int mt = 0; mt < 4; ++mt) {
                float s = mish_f(acch[mt][0]) * wv[0];
                s += mish_f(acch[mt][1]) * wv[1];
                s += mish_f(acch[mt][2]) * wv[2];
                s += mish_f(acch[mt][3]) * wv[3];
                s += __shfl_xor(s, 16); s += __shfl_xor(s, 32);
                asm volatile("" :: "v"(s));           // keep live (no DCE)
                if (quad == 0) red[wave][mt * 16 + l15] = s;
            }
        }
        if (!gskip) {
            const int nb = gnt * 16 + quad * 4;
            const f32x4 gw = (wave < 4) ? *(const f32x4*)&sw2[nb] : *(const f32x4*)&stw2[nb];
#pragma unroll
            for (int mt = 0; mt < 4; ++mt) {
                float s = mish_f(accg[mt][0]) * gw[0];
                s += mish_f(accg[mt][1]) * gw[1];
                s += mish_f(accg[mt][2]) * gw[2];
                s += mish_f(accg[mt][3]) * gw[3];
                s += __shfl_xor(s, 16); s += __shfl_xor(s, 32);
                asm volatile("" :: "v"(s));
                if (quad == 0) red[8 + wave][mt * 16 + l15] = s;
            }
        }
        if constexpr (V != 3) __syncthreads();

        if (tid < 64 && tid < nrows) {
            int row = tid;
            float head = hb2[bb];
#pragma unroll
            for (int w = 0; w < 8; ++w) head += red[w][row];
            float sl = sb2[0], tl = stb2[0];
            if (!gskip) {
#pragma unroll
                for (int w = 0; w < 4; ++w) { sl += red[8 + w][row]; tl += red[12 + w][row]; }
            }
            float sg = sigmoid_f(sl);
            float tg = sigmoid_f(tl);
            float v1 = sfiL[row], v2 = kpL[row];
            float sun_val = sun_b2[0], storm_val = storm_b2[0];
#pragma unroll
            for (int j = 0; j < 8; ++j) {
                sun_val   += tanh_f(v1 * sp[j]      + sun_b1[j])   * sp[8 + j];
                storm_val += tanh_f(v2 * sp[16 + j] + storm_b1[j]) * sp[24 + j];
            }
            float res = head + sg * sun_val + tg * storm_val;
            asm volatile("" :: "v"(res));             // keep live, NO out store
        }
        if constexpr (V != 3) __syncthreads();        // separate reps
    }
}

// ---------------- fallback: pure-VALU scalar kernel (used if ws too small) ----------------
__global__ __launch_bounds__(64) void k_simple(
    const float* __restrict__ x,
    const float* __restrict__ tw1, const float* __restrict__ tb1,
    const float* __restrict__ tw2, const float* __restrict__ tb2,
    const float* __restrict__ hw1, const float* __restrict__ hb1,
    const float* __restrict__ hw2, const float* __restrict__ hb2,
    const float* __restrict__ sw1, const float* __restrict__ sb1,
    const float* __restrict__ sw2, const float* __restrict__ sb2,
    const float* __restrict__ stw1, const float* __restrict__ stb1,
    const float* __restrict__ stw2, const float* __restrict__ stb2,
    const float* __restrict__ sun_w1, const float* __restrict__ sun_b1,
    const float* __restrict__ sun_w2, const float* __restrict__ sun_b2,
    const float* __restrict__ storm_w1, const float* __restrict__ storm_b1,
    const float* __restrict__ storm_w2, const float* __restrict__ storm_b2,
    float* __restrict__ out)
{
    __shared__ u16 t_lds[256 * 64];

    const int lane = threadIdx.x;
    const int r = blockIdx.x * 64 + lane;

    float xr[15];
#pragma unroll
    for (int k = 0; k < 15; ++k) xr[k] = x[r * 18 + k];
    const float sfi = x[r * 18 + 15];
    const float kp  = x[r * 18 + 16];
    const int band  = (int)x[r * 18 + 17];

    for (int tc = 0; tc < 4; ++tc) {
        float acc[64];
#pragma unroll
        for (int j = 0; j < 64; ++j) acc[j] = 0.0f;
        for (int n = 0; n < 512; ++n) {
            float p = tb1[n];
#pragma unroll
            for (int k = 0; k < 15; ++k) p += xr[k] * tw1[k * 512 + n];
            const float a1n = mish_f(p);
            const float* w2 = &tw2[n * 256 + tc * 64];
#pragma unroll
            for (int j = 0; j < 64; ++j) acc[j] += a1n * w2[j];
        }
#pragma unroll
        for (int j = 0; j < 64; ++j)
            t_lds[(tc * 64 + j) * 64 + lane] = f2b(mish_f(acc[j] + tb2[tc * 64 + j]));
    }
    __syncthreads();

    float head_val = 0.0f;
    for (int g = 0; g < 9; ++g) {
        float hs = 0.0f;
        for (int hc = 0; hc < 2; ++hc) {
            float pre[64];
#pragma unroll
            for (int j = 0; j < 64; ++j) pre[j] = 0.0f;
            for (int d = 0; d < 256; ++d) {
                const float td = b2f(t_lds[d * 64 + lane]);
                const float* wv = &hw1[g * 32768 + d * 128 + hc * 64];
#pragma unroll
                for (int j = 0; j < 64; ++j) pre[j] += td * wv[j];
            }
#pragma unroll
            for (int j = 0; j < 64; ++j) {
                const int h = hc * 64 + j;
                hs += mish_f(pre[j] + hb1[g * 128 + h]) * hw2[g * 128 + h];
            }
        }
        head_val += (band == g) ? (hs + hb2[g]) : 0.0f;
    }

    float pre_s[64], pre_t[64];
#pragma unroll
    for (int j = 0; j < 64; ++j) { pre_s[j] = 0.0f; pre_t[j] = 0.0f; }
    for (int d = 0; d < 256; ++d) {
        const float td = b2f(t_lds[d * 64 + lane]);
        const float* ws1 = &sw1[d * 64];
        const float* wt1 = &stw1[d * 64];
#pragma unroll
        for (int j = 0; j < 64; ++j) {
            pre_s[j] += td * ws1[j];
            pre_t[j] += td * wt1[j];
        }
    }
    float ls = sb2[0], lt = stb2[0];
#pragma unroll
    for (int j = 0; j < 64; ++j) {
        ls += mish_f(pre_s[j] + sb1[j]) * sw2[j];
        lt += mish_f(pre_t[j] + stb1[j]) * stw2[j];
    }
    const float sg = sigmoid_f(ls);
    const float tg = sigmoid_f(lt);

    float sun_val = sun_b2[0], storm_val = storm_b2[0];
#pragma unroll
    for (int j = 0; j < 8; ++j) {
        sun_val   += tanh_f(sfi * splus(sun_w1[j])  + sun_b1[j])   * splus(sun_w2[j]);
        storm_val += tanh_f(kp * splus(storm_w1[j]) + storm_b1[j]) * splus(storm_w2[j]);
    }

    out[r] = head_val + sg * sun_val + tg * storm_val;
}

extern "C" void kernel_launch(void* const* d_in, const int* in_sizes, int n_in,
                              void* d_out, int out_size, void* d_ws, size_t ws_size,
                              hipStream_t stream) {
    (void)n_in; (void)out_size;
    const float* x        = (const float*)d_in[0];
    const float* tw1      = (const float*)d_in[1];
    const float* tb1      = (const float*)d_in[2];
    const float* tw2      = (const float*)d_in[3];
    const float* tb2      = (const float*)d_in[4];
    const float* hw1      = (const float*)d_in[5];
    const float* hb1      = (const float*)d_in[6];
    const float* hw2      = (const float*)d_in[7];
    const float* hb2      = (const float*)d_in[8];
    const float* sw1      = (const float*)d_in[9];
    const float* sb1      = (const float*)d_in[10];
    const float* sw2      = (const float*)d_in[11];
    const float* sb2      = (const float*)d_in[12];
    const float* stw1     = (const float*)d_in[13];
    const float* stb1     = (const float*)d_in[14];
    const float* stw2     = (const float*)d_in[15];
    const float* stb2     = (const float*)d_in[16];
    const float* sun_w1   = (const float*)d_in[17];
    const float* sun_b1   = (const float*)d_in[18];
    const float* sun_w2   = (const float*)d_in[19];
    const float* sun_b2   = (const float*)d_in[20];
    const float* storm_w1 = (const float*)d_in[21];
    const float* storm_b1 = (const float*)d_in[22];
    const float* storm_w2 = (const float*)d_in[23];
    const float* storm_b2 = (const float*)d_in[24];

    const int B = in_sizes[0] / 18;

    if (ws_size < (size_t)WS_NEEDED) {
        k_simple<<<B / 64, 64, 0, stream>>>(x, tw1, tb1, tw2, tb2, hw1, hb1, hw2, hb2,
                                            sw1, sb1, sw2, sb2, stw1, stb1, stw2, stb2,
                                            sun_w1, sun_b1, sun_w2, sun_b2,
                                            storm_w1, storm_b1, storm_w2, storm_b2,
                                            (float*)d_out);
        return;
    }

    char* ws = (char*)d_ws;
    int*   perm      = (int*)(ws + WS_PERM);
    int*   cnt       = (int*)(ws + WS_CNT);
    float* sp        = (float*)(ws + WS_SP);
    u16*   W1p       = (u16*)(ws + WS_W1P);
    u16*   W2f       = (u16*)(ws + WS_W2F);
    u16*   HWf       = (u16*)(ws + WS_HW1F);
    u16*   SWf       = (u16*)(ws + WS_SWF);
    u16*   STWf      = (u16*)(ws + WS_STWF);

    hipMemsetAsync(cnt, 0, 18 * 32 * sizeof(int), stream);
    k_pack<<<(B + 511) / 512, 512, 0, stream>>>(x, B, tw1, tw2, hw1, sw1, stw1,
                                                sw2, stw2,
                                                sun_w1, sun_w2, storm_w1, storm_w2,
                                                W1p, W2f, HWf, SWf, STWf, sp, cnt, perm);
    // diagnostic ablations (no out writes; durations read from rocprof table)
    k_abl<2><<<18 * REG_BLOCKS, 512, 0, stream>>>(x, perm, cnt,
                                                  W1p, W2f, HWf, SWf, STWf,
                                                  tb1, tb2, hb1, hw2, hb2,
                                                  sb1, sw2, sb2, stb1, stw2, stb2,
                                                  sp, sun_b1, sun_b2, storm_b1, storm_b2,
                                                  (float*)d_out);
    k_abl<3><<<18 * REG_BLOCKS, 512, 0, stream>>>(x, perm, cnt,
                                                  W1p, W2f, HWf, SWf, STWf,
                                                  tb1, tb2, hb1, hw2, hb2,
                                                  sb1, sw2, sb2, stb1, stw2, stb2,
                                                  sp, sun_b1, sun_b2, storm_b1, storm_b2,
                                                  (float*)d_out);
    k_main<<<18 * REG_BLOCKS, 512, 0, stream>>>(x, perm, cnt,
                                                W1p, W2f, HWf, SWf, STWf,
                                                tb1, tb2, hb1, hw2, hb2,
                                                sb1, sw2, sb2, stb1, stw2, stb2,
                                                sp, sun_b1, sun_b2, storm_b1, storm_b2,
                                                (float*)d_out);
}

// Round 11
// 277.093 us; speedup vs baseline: 3.0327x; 3.0327x over previous
//
#include <hip/hip_runtime.h>
#include <cstdint>

typedef unsigned short u16;
typedef unsigned char u8;
typedef __attribute__((ext_vector_type(8))) __bf16 bf16x8;
typedef __attribute__((ext_vector_type(4))) float f32x4;
typedef __attribute__((ext_vector_type(2))) unsigned u32x2;

#define MFMA16(a, b, c) __builtin_amdgcn_mfma_f32_16x16x32_bf16((a), (b), (c), 0, 0, 0)

__device__ __forceinline__ u16 f2b(float f) {            // SW RNE (prep kernels only)
    union { float f; unsigned u; } v; v.f = f;
    unsigned r = v.u + 0x7fffu + ((v.u >> 16) & 1u);
    return (u16)(r >> 16);
}
__device__ __forceinline__ u16 f2b_hw(float f) {         // HW cvt (hot path)
    union { __bf16 h; u16 u; } cv; cv.h = (__bf16)f; return cv.u;
}
__device__ __forceinline__ float b2f(u16 h) {
    union { unsigned u; float f; } v; v.u = ((unsigned)h) << 16; return v.f;
}
// HW packed cvt: 2 f32 -> 1 dword of 2 bf16 (RNE, same rounding as __bf16 cast).
__device__ __forceinline__ unsigned cvt_pk_bf16(float lo, float hi) {
    unsigned r;
    asm("v_cvt_pk_bf16_f32 %0, %1, %2" : "=v"(r) : "v"(lo), "v"(hi));
    return r;
}
__device__ __forceinline__ float fast_rcp(float x) { return __builtin_amdgcn_rcpf(x); }
// mish(x) = x * tanh(softplus(x)); with s=e^x, tanh(softplus) = s(s+2)/(s(s+2)+2)
__device__ __forceinline__ float mish_f(float x) {
    float s = __expf(fminf(x, 40.0f));
    float p = s * (s + 2.0f);
    return x * p * fast_rcp(p + 2.0f);
}
__device__ __forceinline__ float tanh_f(float y) {
    float e = __expf(2.0f * y);
    return 1.0f - 2.0f * fast_rcp(e + 1.0f);
}
__device__ __forceinline__ float sigmoid_f(float y) {
    return fast_rcp(1.0f + __expf(-y));
}
__device__ __forceinline__ float splus(float w) { return log1pf(__expf(w)); }

// ===================== SESSION LEDGER (final) =====================
// r3 mfma(W,x) operand swap (A-frag==B-frag bytes): -20 us.
// r4 runtime gate-skip (sw2/stw2 all-zero => t@0==0, exact): -20 us.
// r5 prep atomic widening: total-neutral -> prep (~80 us) = launch + k_pack
//    floor, incompressible by counter-chain tuning.
// r6 software pipelining: null -> latency-bound, not issue-bound.
// r7 128-row tile: VGPR spill (262 MB scratch), reverted. Do not retry
//    without halving acc live-set.
// r9 LDS 39,936->35,840 (xA/red aliased into bufmem) + setprio(1) around
//    MFMA clusters: k_main 195->188 us. BEST.
// r10 paid ablation diagnostic: NOGLOBAL and NOBARRIER clones timed
//    IDENTICALLY (~176 us/rep, spill-contaminated but common-mode) ->
//    neither global-load stall nor barrier convoy dominates; residual
//    ~70% stall is distributed dep-chain latency at the 32-waves/CU HW
//    occupancy cap. 64-row/8-wave structure is at its practical floor.
// SQ_LDS_BANK_CONFLICT on this kernel tracks wide-op/address accounting,
// not a schedulable cost (r2/r3/r9 invariance) - not a signal.
// This file = r9 restored byte-for-byte (diagnostics removed).
// ==================================================================

template <int CTRL>
__device__ __forceinline__ float dpp_add(float v) {
    union { float f; int i; } s, p;
    s.f = v;
    p.i = __builtin_amdgcn_update_dpp(0, s.i, CTRL, 0xf, 0xf, true);
    return v + p.f;
}

// ---------------- workspace layout (bytes) ----------------
#define WS_PERM      0u           // int[18*16384] = 294912 slots
#define WS_CNT       1179648u     // int, 18 counters at stride 32 ints (128 B lines)
#define WS_SP        1183744u     // float[32]
#define WS_W1P       1184768u     // u16[512*32]   [n][k]
#define WS_W2F       1217536u     // u16[256*512]  fragment-major NT=16 KB=16
#define WS_HW1F      1479680u     // u16[9*128*256] fragment-major per band NT=8 KB=8
#define WS_SWF       2069504u     // u16[64*256]   fragment-major NT=4 KB=8
#define WS_STWF      2102272u     // u16[64*256]
#define WS_NEEDED    2135040u

#define GFLAG_IDX    600          // int index into cnt area

#define NSUB         2            // sub-regions per band
#define CAPH         16384        // rows per sub-region (E~14563, 15 sigma)
#define REG_BLOCKS   256          // k_main blocks per sub-region = CAPH/64

// Fragment-major (FM): tile (nt,kb) -> 1KB block FMbase+((nt*KB+kb)*64+lane)*8,
// lane=(quad*16+l15) holds W[nt*16+l15][kb*32+quad*8+j].

// ---------------- fused prep: weight packing + atomic counting-sort scatter ----
__global__ __launch_bounds__(512) void k_pack(const float* __restrict__ x, int B,
                       const float* __restrict__ tw1, const float* __restrict__ tw2,
                       const float* __restrict__ hw1,
                       const float* __restrict__ sw1, const float* __restrict__ stw1,
                       const float* __restrict__ sw2, const float* __restrict__ stw2,
                       const float* __restrict__ sun_w1, const float* __restrict__ sun_w2,
                       const float* __restrict__ storm_w1, const float* __restrict__ storm_w2,
                       u16* __restrict__ W1p, u16* __restrict__ W2f, u16* __restrict__ HWf,
                       u16* __restrict__ SWf, u16* __restrict__ STWf,
                       float* __restrict__ sp, int* __restrict__ cnt,
                       int* __restrict__ perm)
{
    __shared__ int wcnt[8][9];
    __shared__ int wpre[8][9];
    __shared__ int bbase[9];
    __shared__ u8 bL[512];
    const int tid  = threadIdx.x;
    const int lane = tid & 63, wave = tid >> 6;
    const int sub  = blockIdx.x & (NSUB - 1);  // parity sub-region
    const int i    = blockIdx.x * 512 + tid;

    // ---- coalesced band extraction: read the block's 512-row slab as float2
    {
        const size_t ebase = (size_t)blockIdx.x * 512 * 18;
        const float2* xs = (const float2*)(x + ebase);
        const size_t etotal = (size_t)B * 18;
        for (int p = tid; p < 4608; p += 512) {
            if (ebase + (size_t)p * 2 + 1 < etotal) {
                float2 v = xs[p];
                int e0 = p * 2;
                int r0 = e0 / 18, c0 = e0 - r0 * 18;   // c0 always even
                if (c0 == 16) bL[r0] = (u8)(int)v.y;   // element 17 = band
            }
        }
    }
    __syncthreads();

    int band = -1, rank = 0;
    if (i < B) band = (int)bL[tid];
    for (int k = 0; k < 9; ++k) {
        unsigned long long m = __ballot(band == k);
        if (band == k) rank = __popcll(m & ((1ull << lane) - 1ull));
        if (lane == 0) wcnt[wave][k] = __popcll(m);
    }
    __syncthreads();
    if (tid < 9) {
        int run = 0;
        for (int w = 0; w < 8; ++w) { wpre[w][tid] = run; run += wcnt[w][tid]; }
        bbase[tid] = atomicAdd(&cnt[(tid * NSUB + sub) * 32], run);
    }
    __syncthreads();
    if (band >= 0)
        perm[(band * NSUB + sub) * CAPH + bbase[band] + wpre[wave][band] + rank] = i;

    // ---- gate-zero detection: if sw2 AND stw2 are entirely zero, the gate
    // GEMMs contribute exactly 0 to the logits (t @ 0 == 0). Exact skip.
    if (blockIdx.x == 0 && tid < 64) {
        bool z = (sw2[tid] == 0.0f) && (stw2[tid] == 0.0f);
        unsigned long long m = __ballot(z);
        if (tid == 0) cnt[GFLAG_IDX] = (m == ~0ull) ? 1 : 0;
    }

    // ---- scalar weights for the tiny monotonic MLPs
    const int gtid = blockIdx.x * 512 + tid;
    if (gtid < 32) {
        const float* srcs[4] = { sun_w1, sun_w2, storm_w1, storm_w2 };
        float w = srcs[gtid >> 3][gtid & 7];
        sp[gtid] = splus(w);
    }
    // ---- bf16 fragment-major weight packing
    const int total = 16384 + 131072 + 294912 + 16384 + 16384;
    for (int i2 = gtid; i2 < total; i2 += 512 * 512) {
        int idx = i2;
        if (idx < 16384) {                         // W1p[n][k] : 512 x 32 (k>=15 zero)
            int n = idx >> 5, k = idx & 31;
            W1p[idx] = (k < 15) ? f2b(tw1[k * 512 + n]) : (u16)0;
        } else if ((idx -= 16384) < 131072) {      // W2f: FM NT=16 KB=16
            int tile = idx >> 9, within = idx & 511;
            int lane2 = within >> 3, j = within & 7;
            int nt = tile >> 4, kb = tile & 15;
            int n = nt * 16 + (lane2 & 15);
            int k = kb * 32 + (lane2 >> 4) * 8 + j;
            W2f[idx] = f2b(tw2[k * 256 + n]);
        } else if ((idx -= 131072) < 294912) {     // HWf: per band g, FM NT=8 KB=8
            int g = idx >> 15, r = idx & 32767;
            int tile = r >> 9, within = r & 511;
            int lane2 = within >> 3, j = within & 7;
            int nt = tile >> 3, kb = tile & 7;
            int n = nt * 16 + (lane2 & 15);
            int k = kb * 32 + (lane2 >> 4) * 8 + j;
            HWf[idx] = f2b(hw1[(g * 256 + k) * 128 + n]);
        } else if ((idx -= 294912) < 16384) {      // SWf: FM NT=4 KB=8
            int tile = idx >> 9, within = idx & 511;
            int lane2 = within >> 3, j = within & 7;
            int nt = tile >> 3, kb = tile & 7;
            int n = nt * 16 + (lane2 & 15);
            int k = kb * 32 + (lane2 >> 4) * 8 + j;
            SWf[idx] = f2b(sw1[k * 64 + n]);
        } else {                                   // STWf
            idx -= 16384;
            int tile = idx >> 9, within = idx & 511;
            int lane2 = within >> 3, j = within & 7;
            int nt = tile >> 3, kb = tile & 7;
            int n = nt * 16 + (lane2 & 15);
            int k = kb * 32 + (lane2 >> 4) * 8 + j;
            STWf[idx] = f2b(stw1[k * 64 + n]);
        }
    }
}

// ---------------- fused main kernel: 64 rows / block, 8 waves, uniform band ----------------
// grid = 18 sub-regions x 256 blocks; band = region>>1; nrows from counter.
// LDS 35,584 B (xA aliased into buf[1], red into buf[0]) -> 4 blocks/CU =
// 32 waves/CU (HW cap). __launch_bounds__(512,4): VGPR cap 128 (compiler ~56).
// DO NOT min-waves=8 (spill); DO NOT 128-row tile (r7 spill).
__global__ __launch_bounds__(512, 4) void k_main(
                       const float* __restrict__ x,
                       const int* __restrict__ perm,
                       const int* __restrict__ cnt,
                       const u16* __restrict__ W1p, const u16* __restrict__ W2f,
                       const u16* __restrict__ HWf,
                       const u16* __restrict__ SWf, const u16* __restrict__ STWf,
                       const float* __restrict__ tb1, const float* __restrict__ tb2,
                       const float* __restrict__ hb1, const float* __restrict__ hw2,
                       const float* __restrict__ hb2,
                       const float* __restrict__ sb1, const float* __restrict__ sw2,
                       const float* __restrict__ sb2,
                       const float* __restrict__ stb1, const float* __restrict__ stw2,
                       const float* __restrict__ stb2,
                       const float* __restrict__ sp,
                       const float* __restrict__ sun_b1, const float* __restrict__ sun_b2,
                       const float* __restrict__ storm_b1, const float* __restrict__ storm_b2,
                       float* __restrict__ out)
{
    const int region = blockIdx.x >> 8;        // 0..17
    const int loc    = blockIdx.x & 255;
    const int bb     = region >> 1;            // band
    const int nr0    = cnt[region * 32] - loc * 64;
    if (nr0 <= 0) return;
    const int nrows  = nr0 > 64 ? 64 : nr0;
    const int rstart = region * CAPH + loc * 64;
    const int gskip  = cnt[GFLAG_IDX];         // 1 -> gate GEMMs are exactly 0

    // Single LDS pool: bufmem is the chunk double-buffer, aliased as
    // t[64][264] for P3. xA overlays buf[1] (dead before buf[1]'s first
    // write, fenced by barrier c=0); red overlays buf[0] (first written
    // after the barrier following the last P3 read).
    __shared__ __align__(16) u16 bufmem[2][64][136];   // 34,816 B
    __shared__ int rowsL[64];
    __shared__ float sfiL[64], kpL[64];
    u16 (*xA)[32]  = (u16(*)[32])&bufmem[1][0][0];
    float (*red)[64] = (float(*)[64])&bufmem[0][0][0];

    int tid = threadIdx.x;
    int lane = tid & 63, wave = tid >> 6;      // wave 0..7
    int quad = lane >> 4, l15 = lane & 15;

    if (tid < 64) {
        int r = rstart + (tid < nrows ? tid : 0);
        rowsL[tid] = perm[r];
    }
    for (int i = tid; i < 64 * 16; i += 512) ((unsigned*)&xA[0][0])[i] = 0u;
    __syncthreads();
    for (int i = tid; i < 64 * 18; i += 512) {
        int r = i / 18, c = i - r * 18;
        float v = x[rowsL[r] * 18 + c];
        if (c < 15) xA[r][c] = f2b_hw(v);
        else if (c == 15) sfiL[r] = v;
        else if (c == 16) kpL[r] = v;
    }
    __syncthreads();

    // x fragments: bytes of A-frag(x) == B-frag(x^T): B[k=quad*8+j][n=row=l15].
    bf16x8 ax[4];
#pragma unroll
    for (int mt = 0; mt < 4; ++mt)
        ax[mt] = *(const bf16x8*)&xA[mt * 16 + l15][quad * 8];

    const int colq = wave * 16 + quad * 4;     // per-wave 16-col block, lane's 4

    // acc2 init = tb2 bias (C-in of first MFMA); saves the epilogue adds.
    f32x4 acc2[2][4];
#pragma unroll
    for (int ntl = 0; ntl < 2; ++ntl) {
        const f32x4 b2v = *(const f32x4*)&tb2[wave * 32 + ntl * 16 + quad * 4];
#pragma unroll
        for (int mt = 0; mt < 4; ++mt) acc2[ntl][mt] = b2v;
    }

    for (int c = 0; c < 4; ++c) {
        // ---- Phase 1: this wave's 16 cols of chunk c, rows land in l15
        f32x4 acc1[4];
        {
            const f32x4 b1v = *(const f32x4*)&tb1[c * 128 + colq];
            bf16x8 bw = *(const bf16x8*)&W1p[(c * 128 + wave * 16 + l15) * 32 + quad * 8];
#pragma unroll
            for (int mt = 0; mt < 4; ++mt) { acc1[mt] = b1v; acc1[mt] = MFMA16(bw, ax[mt], acc1[mt]); }
        }
        u16 (*bufc)[136] = bufmem[c & 1];
#pragma unroll
        for (int mt = 0; mt < 4; ++mt) {
            u32x2 pk;
            pk.x = cvt_pk_bf16(mish_f(acc1[mt][0]), mish_f(acc1[mt][1]));
            pk.y = cvt_pk_bf16(mish_f(acc1[mt][2]), mish_f(acc1[mt][3]));
            *(u32x2*)&bufc[mt * 16 + l15][colq] = pk;
        }
        __syncthreads();
        // ---- Phase 2 partial: acc2 += W2^T @ chunk^T (this wave's 32 cols)
        for (int ks = 0; ks < 4; ++ks) {
            bf16x8 a2[4];
#pragma unroll
            for (int mt = 0; mt < 4; ++mt)
                a2[mt] = *(const bf16x8*)&bufc[mt * 16 + l15][ks * 32 + quad * 8];
            int kb = c * 4 + ks;
            __builtin_amdgcn_s_setprio(1);
#pragma unroll
            for (int ntl = 0; ntl < 2; ++ntl) {
                int nt = wave * 2 + ntl;
                bf16x8 bw = *(const bf16x8*)&W2f[((nt * 16 + kb) << 9) + lane * 8];
#pragma unroll
                for (int mt = 0; mt < 4; ++mt)
                    acc2[ntl][mt] = MFMA16(bw, a2[mt], acc2[ntl][mt]);
            }
            __builtin_amdgcn_s_setprio(0);
        }
    }
    __syncthreads();   // all P2 reads of buf done before aliasing with t

    // ---- t = mish(acc2) -> LDS t[64][264] (aliases bufmem); tb2 already in acc2
    u16 (*tmat)[264] = (u16(*)[264])bufmem;
#pragma unroll
    for (int ntl = 0; ntl < 2; ++ntl) {
        const int colb = wave * 32 + ntl * 16 + quad * 4;
#pragma unroll
        for (int mt = 0; mt < 4; ++mt) {
            u32x2 pk;
            pk.x = cvt_pk_bf16(mish_f(acc2[ntl][mt][0]), mish_f(acc2[ntl][mt][1]));
            pk.y = cvt_pk_bf16(mish_f(acc2[ntl][mt][2]), mish_f(acc2[ntl][mt][3]));
            *(u32x2*)&tmat[mt * 16 + l15][colb] = pk;
        }
    }
    __syncthreads();

    // ---- Phase 3: head nt = wave; gates (unless gskip): waves 0-3 sun,
    // 4-7 storm. K=256. Biases as C-init.
    const u16* Hw = HWf + bb * 32768;
    const u16* Gw = (wave < 4) ? SWf : STWf;
    int gnt = wave & 3;
    f32x4 acch[4], accg[4];
    {
        const f32x4 hb = *(const f32x4*)&hb1[bb * 128 + colq];
#pragma unroll
        for (int mt = 0; mt < 4; ++mt) acch[mt] = hb;
    }
    if (!gskip) {
        const int nb = gnt * 16 + quad * 4;
        const f32x4 gb = (wave < 4) ? *(const f32x4*)&sb1[nb] : *(const f32x4*)&stb1[nb];
#pragma unroll
        for (int mt = 0; mt < 4; ++mt) accg[mt] = gb;
    }
    for (int kb = 0; kb < 8; ++kb) {
        bf16x8 a3[4];
#pragma unroll
        for (int mt = 0; mt < 4; ++mt)
            a3[mt] = *(const bf16x8*)&tmat[mt * 16 + l15][kb * 32 + quad * 8];
        bf16x8 bh = *(const bf16x8*)&Hw[((wave * 8 + kb) << 9) + lane * 8];
        __builtin_amdgcn_s_setprio(1);
#pragma unroll
        for (int mt = 0; mt < 4; ++mt)
            acch[mt] = MFMA16(bh, a3[mt], acch[mt]);
        if (!gskip) {
            bf16x8 bg = *(const bf16x8*)&Gw[((gnt * 8 + kb) << 9) + lane * 8];
#pragma unroll
            for (int mt = 0; mt < 4; ++mt)
                accg[mt] = MFMA16(bg, a3[mt], accg[mt]);
        }
        __builtin_amdgcn_s_setprio(0);
    }
    __syncthreads();   // fence: all P3 tmat reads complete before red (=buf[0]) writes

    // head/gate epilogue: lane owns 4 consecutive cols for row mt*16+l15;
    // fma-chain over its cols, then xor16+xor32 shuffle-adds across quads.
    {
        const f32x4 wv = *(const f32x4*)&hw2[bb * 128 + colq];
#pragma unroll
        for (int mt = 0; mt < 4; ++mt) {
            float s = mish_f(acch[mt][0]) * wv[0];
            s += mish_f(acch[mt][1]) * wv[1];
            s += mish_f(acch[mt][2]) * wv[2];
            s += mish_f(acch[mt][3]) * wv[3];
            s += __shfl_xor(s, 16); s += __shfl_xor(s, 32);
            if (quad == 0) red[wave][mt * 16 + l15] = s;
        }
    }
    if (!gskip) {
        const int nb = gnt * 16 + quad * 4;
        const f32x4 gw = (wave < 4) ? *(const f32x4*)&sw2[nb] : *(const f32x4*)&stw2[nb];
#pragma unroll
        for (int mt = 0; mt < 4; ++mt) {
            float s = mish_f(accg[mt][0]) * gw[0];
            s += mish_f(accg[mt][1]) * gw[1];
            s += mish_f(accg[mt][2]) * gw[2];
            s += mish_f(accg[mt][3]) * gw[3];
            s += __shfl_xor(s, 16); s += __shfl_xor(s, 32);
            if (quad == 0) red[8 + wave][mt * 16 + l15] = s;
        }
    }
    __syncthreads();

    // ---- final scalar math per row (fp32 output)
    if (tid < 64 && tid < nrows) {
        int row = tid;
        float head = hb2[bb];
#pragma unroll
        for (int w = 0; w < 8; ++w) head += red[w][row];
        float sl = sb2[0], tl = stb2[0];
        if (!gskip) {
#pragma unroll
            for (int w = 0; w < 4; ++w) { sl += red[8 + w][row]; tl += red[12 + w][row]; }
        }
        float sg = sigmoid_f(sl);
        float tg = sigmoid_f(tl);
        float v1 = sfiL[row], v2 = kpL[row];
        float sun_val = sun_b2[0], storm_val = storm_b2[0];
#pragma unroll
        for (int j = 0; j < 8; ++j) {
            sun_val   += tanh_f(v1 * sp[j]      + sun_b1[j])   * sp[8 + j];
            storm_val += tanh_f(v2 * sp[16 + j] + storm_b1[j]) * sp[24 + j];
        }
        out[rowsL[row]] = head + sg * sun_val + tg * storm_val;
    }
}

// ---------------- fallback: pure-VALU scalar kernel (used if ws too small) ----------------
__global__ __launch_bounds__(64) void k_simple(
    const float* __restrict__ x,
    const float* __restrict__ tw1, const float* __restrict__ tb1,
    const float* __restrict__ tw2, const float* __restrict__ tb2,
    const float* __restrict__ hw1, const float* __restrict__ hb1,
    const float* __restrict__ hw2, const float* __restrict__ hb2,
    const float* __restrict__ sw1, const float* __restrict__ sb1,
    const float* __restrict__ sw2, const float* __restrict__ sb2,
    const float* __restrict__ stw1, const float* __restrict__ stb1,
    const float* __restrict__ stw2, const float* __restrict__ stb2,
    const float* __restrict__ sun_w1, const float* __restrict__ sun_b1,
    const float* __restrict__ sun_w2, const float* __restrict__ sun_b2,
    const float* __restrict__ storm_w1, const float* __restrict__ storm_b1,
    const float* __restrict__ storm_w2, const float* __restrict__ storm_b2,
    float* __restrict__ out)
{
    __shared__ u16 t_lds[256 * 64];

    const int lane = threadIdx.x;
    const int r = blockIdx.x * 64 + lane;

    float xr[15];
#pragma unroll
    for (int k = 0; k < 15; ++k) xr[k] = x[r * 18 + k];
    const float sfi = x[r * 18 + 15];
    const float kp  = x[r * 18 + 16];
    const int band  = (int)x[r * 18 + 17];

    for (int tc = 0; tc < 4; ++tc) {
        float acc[64];
#pragma unroll
        for (int j = 0; j < 64; ++j) acc[j] = 0.0f;
        for (int n = 0; n < 512; ++n) {
            float p = tb1[n];
#pragma unroll
            for (int k = 0; k < 15; ++k) p += xr[k] * tw1[k * 512 + n];
            const float a1n = mish_f(p);
            const float* w2 = &tw2[n * 256 + tc * 64];
#pragma unroll
            for (int j = 0; j < 64; ++j) acc[j] += a1n * w2[j];
        }
#pragma unroll
        for (int j = 0; j < 64; ++j)
            t_lds[(tc * 64 + j) * 64 + lane] = f2b(mish_f(acc[j] + tb2[tc * 64 + j]));
    }
    __syncthreads();

    float head_val = 0.0f;
    for (int g = 0; g < 9; ++g) {
        float hs = 0.0f;
        for (int hc = 0; hc < 2; ++hc) {
            float pre[64];
#pragma unroll
            for (int j = 0; j < 64; ++j) pre[j] = 0.0f;
            for (int d = 0; d < 256; ++d) {
                const float td = b2f(t_lds[d * 64 + lane]);
                const float* wv = &hw1[g * 32768 + d * 128 + hc * 64];
#pragma unroll
                for (int j = 0; j < 64; ++j) pre[j] += td * wv[j];
            }
#pragma unroll
            for (int j = 0; j < 64; ++j) {
                const int h = hc * 64 + j;
                hs += mish_f(pre[j] + hb1[g * 128 + h]) * hw2[g * 128 + h];
            }
        }
        head_val += (band == g) ? (hs + hb2[g]) : 0.0f;
    }

    float pre_s[64], pre_t[64];
#pragma unroll
    for (int j = 0; j < 64; ++j) { pre_s[j] = 0.0f; pre_t[j] = 0.0f; }
    for (int d = 0; d < 256; ++d) {
        const float td = b2f(t_lds[d * 64 + lane]);
        const float* ws1 = &sw1[d * 64];
        const float* wt1 = &stw1[d * 64];
#pragma unroll
        for (int j = 0; j < 64; ++j) {
            pre_s[j] += td * ws1[j];
            pre_t[j] += td * wt1[j];
        }
    }
    float ls = sb2[0], lt = stb2[0];
#pragma unroll
    for (int j = 0; j < 64; ++j) {
        ls += mish_f(pre_s[j] + sb1[j]) * sw2[j];
        lt += mish_f(pre_t[j] + stb1[j]) * stw2[j];
    }
    const float sg = sigmoid_f(ls);
    const float tg = sigmoid_f(lt);

    float sun_val = sun_b2[0], storm_val = storm_b2[0];
#pragma unroll
    for (int j = 0; j < 8; ++j) {
        sun_val   += tanh_f(sfi * splus(sun_w1[j])  + sun_b1[j])   * splus(sun_w2[j]);
        storm_val += tanh_f(kp * splus(storm_w1[j]) + storm_b1[j]) * splus(storm_w2[j]);
    }

    out[r] = head_val + sg * sun_val + tg * storm_val;
}

extern "C" void kernel_launch(void* const* d_in, const int* in_sizes, int n_in,
                              void* d_out, int out_size, void* d_ws, size_t ws_size,
                              hipStream_t stream) {
    (void)n_in; (void)out_size;
    const float* x        = (const float*)d_in[0];
    const float* tw1      = (const float*)d_in[1];
    const float* tb1      = (const float*)d_in[2];
    const float* tw2      = (const float*)d_in[3];
    const float* tb2      = (const float*)d_in[4];
    const float* hw1      = (const float*)d_in[5];
    const float* hb1      = (const float*)d_in[6];
    const float* hw2      = (const float*)d_in[7];
    const float* hb2      = (const float*)d_in[8];
    const float* sw1      = (const float*)d_in[9];
    const float* sb1      = (const float*)d_in[10];
    const float* sw2      = (const float*)d_in[11];
    const float* sb2      = (const float*)d_in[12];
    const float* stw1     = (const float*)d_in[13];
    const float* stb1     = (const float*)d_in[14];
    const float* stw2     = (const float*)d_in[15];
    const float* stb2     = (const float*)d_in[16];
    const float* sun_w1   = (const float*)d_in[17];
    const float* sun_b1   = (const float*)d_in[18];
    const float* sun_w2   = (const float*)d_in[19];
    const float* sun_b2   = (const float*)d_in[20];
    const float* storm_w1 = (const float*)d_in[21];
    const float* storm_b1 = (const float*)d_in[22];
    const float* storm_w2 = (const float*)d_in[23];
    const float* storm_b2 = (const float*)d_in[24];

    const int B = in_sizes[0] / 18;

    if (ws_size < (size_t)WS_NEEDED) {
        k_simple<<<B / 64, 64, 0, stream>>>(x, tw1, tb1, tw2, tb2, hw1, hb1, hw2, hb2,
                                            sw1, sb1, sw2, sb2, stw1, stb1, stw2, stb2,
                                            sun_w1, sun_b1, sun_w2, sun_b2,
                                            storm_w1, storm_b1, storm_w2, storm_b2,
                                            (float*)d_out);
        return;
    }

    char* ws = (char*)d_ws;
    int*   perm      = (int*)(ws + WS_PERM);
    int*   cnt       = (int*)(ws + WS_CNT);
    float* sp        = (float*)(ws + WS_SP);
    u16*   W1p       = (u16*)(ws + WS_W1P);
    u16*   W2f       = (u16*)(ws + WS_W2F);
    u16*   HWf       = (u16*)(ws + WS_HW1F);
    u16*   SWf       = (u16*)(ws + WS_SWF);
    u16*   STWf      = (u16*)(ws + WS_STWF);

    hipMemsetAsync(cnt, 0, 18 * 32 * sizeof(int), stream);
    k_pack<<<(B + 511) / 512, 512, 0, stream>>>(x, B, tw1, tw2, hw1, sw1, stw1,
                                                sw2, stw2,
                                                sun_w1, sun_w2, storm_w1, storm_w2,
                                                W1p, W2f, HWf, SWf, STWf, sp, cnt, perm);
    k_main<<<18 * REG_BLOCKS, 512, 0, stream>>>(x, perm, cnt,
                                                W1p, W2f, HWf, SWf, STWf,
                                                tb1, tb2, hb1, hw2, hb2,
                                                sb1, sw2, sb2, stb1, stw2, stb2,
                                                sp, sun_b1, sun_b2, storm_b1, storm_b2,
                                                (float*)d_out);
}

// Round 12
// 275.147 us; speedup vs baseline: 3.0542x; 1.0071x over previous
//
#include <hip/hip_runtime.h>
#include <cstdint>

typedef unsigned short u16;
typedef unsigned char u8;
typedef __attribute__((ext_vector_type(8))) __bf16 bf16x8;
typedef __attribute__((ext_vector_type(4))) float f32x4;
typedef __attribute__((ext_vector_type(2))) unsigned u32x2;

#define MFMA16(a, b, c) __builtin_amdgcn_mfma_f32_16x16x32_bf16((a), (b), (c), 0, 0, 0)

__device__ __forceinline__ u16 f2b(float f) {            // SW RNE (prep kernels only)
    union { float f; unsigned u; } v; v.f = f;
    unsigned r = v.u + 0x7fffu + ((v.u >> 16) & 1u);
    return (u16)(r >> 16);
}
__device__ __forceinline__ u16 f2b_hw(float f) {         // HW cvt (hot path)
    union { __bf16 h; u16 u; } cv; cv.h = (__bf16)f; return cv.u;
}
__device__ __forceinline__ float b2f(u16 h) {
    union { unsigned u; float f; } v; v.u = ((unsigned)h) << 16; return v.f;
}
// HW packed cvt: 2 f32 -> 1 dword of 2 bf16 (RNE, same rounding as __bf16 cast).
__device__ __forceinline__ unsigned cvt_pk_bf16(float lo, float hi) {
    unsigned r;
    asm("v_cvt_pk_bf16_f32 %0, %1, %2" : "=v"(r) : "v"(lo), "v"(hi));
    return r;
}
__device__ __forceinline__ float fast_rcp(float x) { return __builtin_amdgcn_rcpf(x); }
// mish(x) = x * tanh(softplus(x)); with s=e^x, tanh(softplus) = s(s+2)/(s(s+2)+2)
__device__ __forceinline__ float mish_f(float x) {
    float s = __expf(fminf(x, 40.0f));
    float p = s * (s + 2.0f);
    return x * p * fast_rcp(p + 2.0f);
}
__device__ __forceinline__ float tanh_f(float y) {
    float e = __expf(2.0f * y);
    return 1.0f - 2.0f * fast_rcp(e + 1.0f);
}
__device__ __forceinline__ float sigmoid_f(float y) {
    return fast_rcp(1.0f + __expf(-y));
}
__device__ __forceinline__ float splus(float w) { return log1pf(__expf(w)); }

// LDS-only barrier (T4-lite): drains OWN ds ops (lgkmcnt) for cross-wave LDS
// visibility, then raw s_barrier WITHOUT the vmcnt(0) drain that
// __syncthreads() emits. Global weight loads (read-only, never cross-wave
// through a barrier) stay in flight across phases; the compiler still
// auto-inserts vmcnt waits before each load's USE. HK/8-phase pattern.
__device__ __forceinline__ void bar_lgkm() {
    asm volatile("s_waitcnt lgkmcnt(0)" ::: "memory");
    __builtin_amdgcn_s_barrier();
}

// ===================== SESSION LEDGER =====================
// r3 mfma(W,x) operand swap (A-frag==B-frag bytes): -20 us.
// r4 runtime gate-skip (sw2/stw2 all-zero => t@0==0, exact): -20 us.
// r5 prep atomic widening: total-neutral -> prep (~90 us) = launch + k_pack
//    floor, incompressible by counter-chain tuning.
// r6 software pipelining (with draining __syncthreads): null.
// r7 128-row tile: VGPR spill (262 MB scratch), reverted.
// r9 LDS 39,936->35,840 (xA/red aliased into bufmem) + setprio around MFMA:
//    k_main 195->188. r11 reproduced: 186-190 / total 277.1 (BEST).
// r10 ablation (spill-contaminated, common-mode): NOGLOBAL == NOBARRIER ->
//    no single dominant stall; each lever <=12 us at the 32-waves/CU cap.
// r12 (this): replace k_main's 10 __syncthreads with lgkmcnt(0)+raw s_barrier
//    so weight loads survive barriers (hipcc's conservative vmcnt(0) drain at
//    __syncthreads is the documented ~20% GEMM stall). Correctness-identical;
//    clean A/B vs r11. If null -> practical floor ~277 us declared.
// SQ_LDS_BANK_CONFLICT here tracks wide-op/address accounting, not a
// schedulable cost (r2/r3/r9 invariance) - not a signal.
// ==========================================================

template <int CTRL>
__device__ __forceinline__ float dpp_add(float v) {
    union { float f; int i; } s, p;
    s.f = v;
    p.i = __builtin_amdgcn_update_dpp(0, s.i, CTRL, 0xf, 0xf, true);
    return v + p.f;
}

// ---------------- workspace layout (bytes) ----------------
#define WS_PERM      0u           // int[18*16384] = 294912 slots
#define WS_CNT       1179648u     // int, 18 counters at stride 32 ints (128 B lines)
#define WS_SP        1183744u     // float[32]
#define WS_W1P       1184768u     // u16[512*32]   [n][k]
#define WS_W2F       1217536u     // u16[256*512]  fragment-major NT=16 KB=16
#define WS_HW1F      1479680u     // u16[9*128*256] fragment-major per band NT=8 KB=8
#define WS_SWF       2069504u     // u16[64*256]   fragment-major NT=4 KB=8
#define WS_STWF      2102272u     // u16[64*256]
#define WS_NEEDED    2135040u

#define GFLAG_IDX    600          // int index into cnt area

#define NSUB         2            // sub-regions per band
#define CAPH         16384        // rows per sub-region (E~14563, 15 sigma)
#define REG_BLOCKS   256          // k_main blocks per sub-region = CAPH/64

// Fragment-major (FM): tile (nt,kb) -> 1KB block FMbase+((nt*KB+kb)*64+lane)*8,
// lane=(quad*16+l15) holds W[nt*16+l15][kb*32+quad*8+j].

// ---------------- fused prep: weight packing + atomic counting-sort scatter ----
__global__ __launch_bounds__(512) void k_pack(const float* __restrict__ x, int B,
                       const float* __restrict__ tw1, const float* __restrict__ tw2,
                       const float* __restrict__ hw1,
                       const float* __restrict__ sw1, const float* __restrict__ stw1,
                       const float* __restrict__ sw2, const float* __restrict__ stw2,
                       const float* __restrict__ sun_w1, const float* __restrict__ sun_w2,
                       const float* __restrict__ storm_w1, const float* __restrict__ storm_w2,
                       u16* __restrict__ W1p, u16* __restrict__ W2f, u16* __restrict__ HWf,
                       u16* __restrict__ SWf, u16* __restrict__ STWf,
                       float* __restrict__ sp, int* __restrict__ cnt,
                       int* __restrict__ perm)
{
    __shared__ int wcnt[8][9];
    __shared__ int wpre[8][9];
    __shared__ int bbase[9];
    __shared__ u8 bL[512];
    const int tid  = threadIdx.x;
    const int lane = tid & 63, wave = tid >> 6;
    const int sub  = blockIdx.x & (NSUB - 1);  // parity sub-region
    const int i    = blockIdx.x * 512 + tid;

    // ---- coalesced band extraction: read the block's 512-row slab as float2
    {
        const size_t ebase = (size_t)blockIdx.x * 512 * 18;
        const float2* xs = (const float2*)(x + ebase);
        const size_t etotal = (size_t)B * 18;
        for (int p = tid; p < 4608; p += 512) {
            if (ebase + (size_t)p * 2 + 1 < etotal) {
                float2 v = xs[p];
                int e0 = p * 2;
                int r0 = e0 / 18, c0 = e0 - r0 * 18;   // c0 always even
                if (c0 == 16) bL[r0] = (u8)(int)v.y;   // element 17 = band
            }
        }
    }
    __syncthreads();

    int band = -1, rank = 0;
    if (i < B) band = (int)bL[tid];
    for (int k = 0; k < 9; ++k) {
        unsigned long long m = __ballot(band == k);
        if (band == k) rank = __popcll(m & ((1ull << lane) - 1ull));
        if (lane == 0) wcnt[wave][k] = __popcll(m);
    }
    __syncthreads();
    if (tid < 9) {
        int run = 0;
        for (int w = 0; w < 8; ++w) { wpre[w][tid] = run; run += wcnt[w][tid]; }
        bbase[tid] = atomicAdd(&cnt[(tid * NSUB + sub) * 32], run);
    }
    __syncthreads();
    if (band >= 0)
        perm[(band * NSUB + sub) * CAPH + bbase[band] + wpre[wave][band] + rank] = i;

    // ---- gate-zero detection: if sw2 AND stw2 are entirely zero, the gate
    // GEMMs contribute exactly 0 to the logits (t @ 0 == 0). Exact skip.
    if (blockIdx.x == 0 && tid < 64) {
        bool z = (sw2[tid] == 0.0f) && (stw2[tid] == 0.0f);
        unsigned long long m = __ballot(z);
        if (tid == 0) cnt[GFLAG_IDX] = (m == ~0ull) ? 1 : 0;
    }

    // ---- scalar weights for the tiny monotonic MLPs
    const int gtid = blockIdx.x * 512 + tid;
    if (gtid < 32) {
        const float* srcs[4] = { sun_w1, sun_w2, storm_w1, storm_w2 };
        float w = srcs[gtid >> 3][gtid & 7];
        sp[gtid] = splus(w);
    }
    // ---- bf16 fragment-major weight packing
    const int total = 16384 + 131072 + 294912 + 16384 + 16384;
    for (int i2 = gtid; i2 < total; i2 += 512 * 512) {
        int idx = i2;
        if (idx < 16384) {                         // W1p[n][k] : 512 x 32 (k>=15 zero)
            int n = idx >> 5, k = idx & 31;
            W1p[idx] = (k < 15) ? f2b(tw1[k * 512 + n]) : (u16)0;
        } else if ((idx -= 16384) < 131072) {      // W2f: FM NT=16 KB=16
            int tile = idx >> 9, within = idx & 511;
            int lane2 = within >> 3, j = within & 7;
            int nt = tile >> 4, kb = tile & 15;
            int n = nt * 16 + (lane2 & 15);
            int k = kb * 32 + (lane2 >> 4) * 8 + j;
            W2f[idx] = f2b(tw2[k * 256 + n]);
        } else if ((idx -= 131072) < 294912) {     // HWf: per band g, FM NT=8 KB=8
            int g = idx >> 15, r = idx & 32767;
            int tile = r >> 9, within = r & 511;
            int lane2 = within >> 3, j = within & 7;
            int nt = tile >> 3, kb = tile & 7;
            int n = nt * 16 + (lane2 & 15);
            int k = kb * 32 + (lane2 >> 4) * 8 + j;
            HWf[idx] = f2b(hw1[(g * 256 + k) * 128 + n]);
        } else if ((idx -= 294912) < 16384) {      // SWf: FM NT=4 KB=8
            int tile = idx >> 9, within = idx & 511;
            int lane2 = within >> 3, j = within & 7;
            int nt = tile >> 3, kb = tile & 7;
            int n = nt * 16 + (lane2 & 15);
            int k = kb * 32 + (lane2 >> 4) * 8 + j;
            SWf[idx] = f2b(sw1[k * 64 + n]);
        } else {                                   // STWf
            idx -= 16384;
            int tile = idx >> 9, within = idx & 511;
            int lane2 = within >> 3, j = within & 7;
            int nt = tile >> 3, kb = tile & 7;
            int n = nt * 16 + (lane2 & 15);
            int k = kb * 32 + (lane2 >> 4) * 8 + j;
            STWf[idx] = f2b(stw1[k * 64 + n]);
        }
    }
}

// ---------------- fused main kernel: 64 rows / block, 8 waves, uniform band ----------------
// grid = 18 sub-regions x 256 blocks; band = region>>1; nrows from counter.
// LDS 35,584 B (xA aliased into buf[1], red into buf[0]) -> 4 blocks/CU =
// 32 waves/CU (HW cap). __launch_bounds__(512,4): VGPR cap 128.
// All inter-phase barriers are bar_lgkm() (no vmcnt drain) - see header note.
// DO NOT min-waves=8 (spill); DO NOT 128-row tile (r7 spill).
__global__ __launch_bounds__(512, 4) void k_main(
                       const float* __restrict__ x,
                       const int* __restrict__ perm,
                       const int* __restrict__ cnt,
                       const u16* __restrict__ W1p, const u16* __restrict__ W2f,
                       const u16* __restrict__ HWf,
                       const u16* __restrict__ SWf, const u16* __restrict__ STWf,
                       const float* __restrict__ tb1, const float* __restrict__ tb2,
                       const float* __restrict__ hb1, const float* __restrict__ hw2,
                       const float* __restrict__ hb2,
                       const float* __restrict__ sb1, const float* __restrict__ sw2,
                       const float* __restrict__ sb2,
                       const float* __restrict__ stb1, const float* __restrict__ stw2,
                       const float* __restrict__ stb2,
                       const float* __restrict__ sp,
                       const float* __restrict__ sun_b1, const float* __restrict__ sun_b2,
                       const float* __restrict__ storm_b1, const float* __restrict__ storm_b2,
                       float* __restrict__ out)
{
    const int region = blockIdx.x >> 8;        // 0..17
    const int loc    = blockIdx.x & 255;
    const int bb     = region >> 1;            // band
    const int nr0    = cnt[region * 32] - loc * 64;
    if (nr0 <= 0) return;
    const int nrows  = nr0 > 64 ? 64 : nr0;
    const int rstart = region * CAPH + loc * 64;
    const int gskip  = cnt[GFLAG_IDX];         // 1 -> gate GEMMs are exactly 0

    // Single LDS pool: bufmem is the chunk double-buffer, aliased as
    // t[64][264] for P3. xA overlays buf[1] (dead before buf[1]'s first
    // write, fenced by barrier c=0); red overlays buf[0] (first written
    // after the barrier following the last P3 read).
    __shared__ __align__(16) u16 bufmem[2][64][136];   // 34,816 B
    __shared__ int rowsL[64];
    __shared__ float sfiL[64], kpL[64];
    u16 (*xA)[32]  = (u16(*)[32])&bufmem[1][0][0];
    float (*red)[64] = (float(*)[64])&bufmem[0][0][0];

    int tid = threadIdx.x;
    int lane = tid & 63, wave = tid >> 6;      // wave 0..7
    int quad = lane >> 4, l15 = lane & 15;

    if (tid < 64) {
        int r = rstart + (tid < nrows ? tid : 0);
        rowsL[tid] = perm[r];
    }
    for (int i = tid; i < 64 * 16; i += 512) ((unsigned*)&xA[0][0])[i] = 0u;
    bar_lgkm();
    for (int i = tid; i < 64 * 18; i += 512) {
        int r = i / 18, c = i - r * 18;
        float v = x[rowsL[r] * 18 + c];
        if (c < 15) xA[r][c] = f2b_hw(v);
        else if (c == 15) sfiL[r] = v;
        else if (c == 16) kpL[r] = v;
    }
    bar_lgkm();

    // x fragments: bytes of A-frag(x) == B-frag(x^T): B[k=quad*8+j][n=row=l15].
    bf16x8 ax[4];
#pragma unroll
    for (int mt = 0; mt < 4; ++mt)
        ax[mt] = *(const bf16x8*)&xA[mt * 16 + l15][quad * 8];

    const int colq = wave * 16 + quad * 4;     // per-wave 16-col block, lane's 4

    // acc2 init = tb2 bias (C-in of first MFMA); saves the epilogue adds.
    f32x4 acc2[2][4];
#pragma unroll
    for (int ntl = 0; ntl < 2; ++ntl) {
        const f32x4 b2v = *(const f32x4*)&tb2[wave * 32 + ntl * 16 + quad * 4];
#pragma unroll
        for (int mt = 0; mt < 4; ++mt) acc2[ntl][mt] = b2v;
    }

    for (int c = 0; c < 4; ++c) {
        // ---- Phase 1: this wave's 16 cols of chunk c, rows land in l15
        f32x4 acc1[4];
        {
            const f32x4 b1v = *(const f32x4*)&tb1[c * 128 + colq];
            bf16x8 bw = *(const bf16x8*)&W1p[(c * 128 + wave * 16 + l15) * 32 + quad * 8];
#pragma unroll
            for (int mt = 0; mt < 4; ++mt) { acc1[mt] = b1v; acc1[mt] = MFMA16(bw, ax[mt], acc1[mt]); }
        }
        u16 (*bufc)[136] = bufmem[c & 1];
#pragma unroll
        for (int mt = 0; mt < 4; ++mt) {
            u32x2 pk;
            pk.x = cvt_pk_bf16(mish_f(acc1[mt][0]), mish_f(acc1[mt][1]));
            pk.y = cvt_pk_bf16(mish_f(acc1[mt][2]), mish_f(acc1[mt][3]));
            *(u32x2*)&bufc[mt * 16 + l15][colq] = pk;
        }
        bar_lgkm();
        // ---- Phase 2 partial: acc2 += W2^T @ chunk^T (this wave's 32 cols)
        for (int ks = 0; ks < 4; ++ks) {
            bf16x8 a2[4];
#pragma unroll
            for (int mt = 0; mt < 4; ++mt)
                a2[mt] = *(const bf16x8*)&bufc[mt * 16 + l15][ks * 32 + quad * 8];
            int kb = c * 4 + ks;
            __builtin_amdgcn_s_setprio(1);
#pragma unroll
            for (int ntl = 0; ntl < 2; ++ntl) {
                int nt = wave * 2 + ntl;
                bf16x8 bw = *(const bf16x8*)&W2f[((nt * 16 + kb) << 9) + lane * 8];
#pragma unroll
                for (int mt = 0; mt < 4; ++mt)
                    acc2[ntl][mt] = MFMA16(bw, a2[mt], acc2[ntl][mt]);
            }
            __builtin_amdgcn_s_setprio(0);
        }
    }
    bar_lgkm();   // all P2 reads of buf done before aliasing with t

    // ---- t = mish(acc2) -> LDS t[64][264] (aliases bufmem); tb2 already in acc2
    u16 (*tmat)[264] = (u16(*)[264])bufmem;
#pragma unroll
    for (int ntl = 0; ntl < 2; ++ntl) {
        const int colb = wave * 32 + ntl * 16 + quad * 4;
#pragma unroll
        for (int mt = 0; mt < 4; ++mt) {
            u32x2 pk;
            pk.x = cvt_pk_bf16(mish_f(acc2[ntl][mt][0]), mish_f(acc2[ntl][mt][1]));
            pk.y = cvt_pk_bf16(mish_f(acc2[ntl][mt][2]), mish_f(acc2[ntl][mt][3]));
            *(u32x2*)&tmat[mt * 16 + l15][colb] = pk;
        }
    }
    bar_lgkm();

    // ---- Phase 3: head nt = wave; gates (unless gskip): waves 0-3 sun,
    // 4-7 storm. K=256. Biases as C-init.
    const u16* Hw = HWf + bb * 32768;
    const u16* Gw = (wave < 4) ? SWf : STWf;
    int gnt = wave & 3;
    f32x4 acch[4], accg[4];
    {
        const f32x4 hb = *(const f32x4*)&hb1[bb * 128 + colq];
#pragma unroll
        for (int mt = 0; mt < 4; ++mt) acch[mt] = hb;
    }
    if (!gskip) {
        const int nb = gnt * 16 + quad * 4;
        const f32x4 gb = (wave < 4) ? *(const f32x4*)&sb1[nb] : *(const f32x4*)&stb1[nb];
#pragma unroll
        for (int mt = 0; mt < 4; ++mt) accg[mt] = gb;
    }
    for (int kb = 0; kb < 8; ++kb) {
        bf16x8 a3[4];
#pragma unroll
        for (int mt = 0; mt < 4; ++mt)
            a3[mt] = *(const bf16x8*)&tmat[mt * 16 + l15][kb * 32 + quad * 8];
        bf16x8 bh = *(const bf16x8*)&Hw[((wave * 8 + kb) << 9) + lane * 8];
        __builtin_amdgcn_s_setprio(1);
#pragma unroll
        for (int mt = 0; mt < 4; ++mt)
            acch[mt] = MFMA16(bh, a3[mt], acch[mt]);
        if (!gskip) {
            bf16x8 bg = *(const bf16x8*)&Gw[((gnt * 8 + kb) << 9) + lane * 8];
#pragma unroll
            for (int mt = 0; mt < 4; ++mt)
                accg[mt] = MFMA16(bg, a3[mt], accg[mt]);
        }
        __builtin_amdgcn_s_setprio(0);
    }
    bar_lgkm();   // fence: all P3 tmat reads complete before red (=buf[0]) writes

    // head/gate epilogue: lane owns 4 consecutive cols for row mt*16+l15;
    // fma-chain over its cols, then xor16+xor32 shuffle-adds across quads.
    {
        const f32x4 wv = *(const f32x4*)&hw2[bb * 128 + colq];
#pragma unroll
        for (int mt = 0; mt < 4; ++mt) {
            float s = mish_f(acch[mt][0]) * wv[0];
            s += mish_f(acch[mt][1]) * wv[1];
            s += mish_f(acch[mt][2]) * wv[2];
            s += mish_f(acch[mt][3]) * wv[3];
            s += __shfl_xor(s, 16); s += __shfl_xor(s, 32);
            if (quad == 0) red[wave][mt * 16 + l15] = s;
        }
    }
    if (!gskip) {
        const int nb = gnt * 16 + quad * 4;
        const f32x4 gw = (wave < 4) ? *(const f32x4*)&sw2[nb] : *(const f32x4*)&stw2[nb];
#pragma unroll
        for (int mt = 0; mt < 4; ++mt) {
            float s = mish_f(accg[mt][0]) * gw[0];
            s += mish_f(accg[mt][1]) * gw[1];
            s += mish_f(accg[mt][2]) * gw[2];
            s += mish_f(accg[mt][3]) * gw[3];
            s += __shfl_xor(s, 16); s += __shfl_xor(s, 32);
            if (quad == 0) red[8 + wave][mt * 16 + l15] = s;
        }
    }
    bar_lgkm();

    // ---- final scalar math per row (fp32 output)
    if (tid < 64 && tid < nrows) {
        int row = tid;
        float head = hb2[bb];
#pragma unroll
        for (int w = 0; w < 8; ++w) head += red[w][row];
        float sl = sb2[0], tl = stb2[0];
        if (!gskip) {
#pragma unroll
            for (int w = 0; w < 4; ++w) { sl += red[8 + w][row]; tl += red[12 + w][row]; }
        }
        float sg = sigmoid_f(sl);
        float tg = sigmoid_f(tl);
        float v1 = sfiL[row], v2 = kpL[row];
        float sun_val = sun_b2[0], storm_val = storm_b2[0];
#pragma unroll
        for (int j = 0; j < 8; ++j) {
            sun_val   += tanh_f(v1 * sp[j]      + sun_b1[j])   * sp[8 + j];
            storm_val += tanh_f(v2 * sp[16 + j] + storm_b1[j]) * sp[24 + j];
        }
        out[rowsL[row]] = head + sg * sun_val + tg * storm_val;
    }
}

// ---------------- fallback: pure-VALU scalar kernel (used if ws too small) ----------------
__global__ __launch_bounds__(64) void k_simple(
    const float* __restrict__ x,
    const float* __restrict__ tw1, const float* __restrict__ tb1,
    const float* __restrict__ tw2, const float* __restrict__ tb2,
    const float* __restrict__ hw1, const float* __restrict__ hb1,
    const float* __restrict__ hw2, const float* __restrict__ hb2,
    const float* __restrict__ sw1, const float* __restrict__ sb1,
    const float* __restrict__ sw2, const float* __restrict__ sb2,
    const float* __restrict__ stw1, const float* __restrict__ stb1,
    const float* __restrict__ stw2, const float* __restrict__ stb2,
    const float* __restrict__ sun_w1, const float* __restrict__ sun_b1,
    const float* __restrict__ sun_w2, const float* __restrict__ sun_b2,
    const float* __restrict__ storm_w1, const float* __restrict__ storm_b1,
    const float* __restrict__ storm_w2, const float* __restrict__ storm_b2,
    float* __restrict__ out)
{
    __shared__ u16 t_lds[256 * 64];

    const int lane = threadIdx.x;
    const int r = blockIdx.x * 64 + lane;

    float xr[15];
#pragma unroll
    for (int k = 0; k < 15; ++k) xr[k] = x[r * 18 + k];
    const float sfi = x[r * 18 + 15];
    const float kp  = x[r * 18 + 16];
    const int band  = (int)x[r * 18 + 17];

    for (int tc = 0; tc < 4; ++tc) {
        float acc[64];
#pragma unroll
        for (int j = 0; j < 64; ++j) acc[j] = 0.0f;
        for (int n = 0; n < 512; ++n) {
            float p = tb1[n];
#pragma unroll
            for (int k = 0; k < 15; ++k) p += xr[k] * tw1[k * 512 + n];
            const float a1n = mish_f(p);
            const float* w2 = &tw2[n * 256 + tc * 64];
#pragma unroll
            for (int j = 0; j < 64; ++j) acc[j] += a1n * w2[j];
        }
#pragma unroll
        for (int j = 0; j < 64; ++j)
            t_lds[(tc * 64 + j) * 64 + lane] = f2b(mish_f(acc[j] + tb2[tc * 64 + j]));
    }
    __syncthreads();

    float head_val = 0.0f;
    for (int g = 0; g < 9; ++g) {
        float hs = 0.0f;
        for (int hc = 0; hc < 2; ++hc) {
            float pre[64];
#pragma unroll
            for (int j = 0; j < 64; ++j) pre[j] = 0.0f;
            for (int d = 0; d < 256; ++d) {
                const float td = b2f(t_lds[d * 64 + lane]);
                const float* wv = &hw1[g * 32768 + d * 128 + hc * 64];
#pragma unroll
                for (int j = 0; j < 64; ++j) pre[j] += td * wv[j];
            }
#pragma unroll
            for (int j = 0; j < 64; ++j) {
                const int h = hc * 64 + j;
                hs += mish_f(pre[j] + hb1[g * 128 + h]) * hw2[g * 128 + h];
            }
        }
        head_val += (band == g) ? (hs + hb2[g]) : 0.0f;
    }

    float pre_s[64], pre_t[64];
#pragma unroll
    for (int j = 0; j < 64; ++j) { pre_s[j] = 0.0f; pre_t[j] = 0.0f; }
    for (int d = 0; d < 256; ++d) {
        const float td = b2f(t_lds[d * 64 + lane]);
        const float* ws1 = &sw1[d * 64];
        const float* wt1 = &stw1[d * 64];
#pragma unroll
        for (int j = 0; j < 64; ++j) {
            pre_s[j] += td * ws1[j];
            pre_t[j] += td * wt1[j];
        }
    }
    float ls = sb2[0], lt = stb2[0];
#pragma unroll
    for (int j = 0; j < 64; ++j) {
        ls += mish_f(pre_s[j] + sb1[j]) * sw2[j];
        lt += mish_f(pre_t[j] + stb1[j]) * stw2[j];
    }
    const float sg = sigmoid_f(ls);
    const float tg = sigmoid_f(lt);

    float sun_val = sun_b2[0], storm_val = storm_b2[0];
#pragma unroll
    for (int j = 0; j < 8; ++j) {
        sun_val   += tanh_f(sfi * splus(sun_w1[j])  + sun_b1[j])   * splus(sun_w2[j]);
        storm_val += tanh_f(kp * splus(storm_w1[j]) + storm_b1[j]) * splus(storm_w2[j]);
    }

    out[r] = head_val + sg * sun_val + tg * storm_val;
}

extern "C" void kernel_launch(void* const* d_in, const int* in_sizes, int n_in,
                              void* d_out, int out_size, void* d_ws, size_t ws_size,
                              hipStream_t stream) {
    (void)n_in; (void)out_size;
    const float* x        = (const float*)d_in[0];
    const float* tw1      = (const float*)d_in[1];
    const float* tb1      = (const float*)d_in[2];
    const float* tw2      = (const float*)d_in[3];
    const float* tb2      = (const float*)d_in[4];
    const float* hw1      = (const float*)d_in[5];
    const float* hb1      = (const float*)d_in[6];
    const float* hw2      = (const float*)d_in[7];
    const float* hb2      = (const float*)d_in[8];
    const float* sw1      = (const float*)d_in[9];
    const float* sb1      = (const float*)d_in[10];
    const float* sw2      = (const float*)d_in[11];
    const float* sb2      = (const float*)d_in[12];
    const float* stw1     = (const float*)d_in[13];
    const float* stb1     = (const float*)d_in[14];
    const float* stw2     = (const float*)d_in[15];
    const float* stb2     = (const float*)d_in[16];
    const float* sun_w1   = (const float*)d_in[17];
    const float* sun_b1   = (const float*)d_in[18];
    const float* sun_w2   = (const float*)d_in[19];
    const float* sun_b2   = (const float*)d_in[20];
    const float* storm_w1 = (const float*)d_in[21];
    const float* storm_b1 = (const float*)d_in[22];
    const float* storm_w2 = (const float*)d_in[23];
    const float* storm_b2 = (const float*)d_in[24];

    const int B = in_sizes[0] / 18;

    if (ws_size < (size_t)WS_NEEDED) {
        k_simple<<<B / 64, 64, 0, stream>>>(x, tw1, tb1, tw2, tb2, hw1, hb1, hw2, hb2,
                                            sw1, sb1, sw2, sb2, stw1, stb1, stw2, stb2,
                                            sun_w1, sun_b1, sun_w2, sun_b2,
                                            storm_w1, storm_b1, storm_w2, storm_b2,
                                            (float*)d_out);
        return;
    }

    char* ws = (char*)d_ws;
    int*   perm      = (int*)(ws + WS_PERM);
    int*   cnt       = (int*)(ws + WS_CNT);
    float* sp        = (float*)(ws + WS_SP);
    u16*   W1p       = (u16*)(ws + WS_W1P);
    u16*   W2f       = (u16*)(ws + WS_W2F);
    u16*   HWf       = (u16*)(ws + WS_HW1F);
    u16*   SWf       = (u16*)(ws + WS_SWF);
    u16*   STWf      = (u16*)(ws + WS_STWF);

    hipMemsetAsync(cnt, 0, 18 * 32 * sizeof(int), stream);
    k_pack<<<(B + 511) / 512, 512, 0, stream>>>(x, B, tw1, tw2, hw1, sw1, stw1,
                                                sw2, stw2,
                                                sun_w1, sun_w2, storm_w1, storm_w2,
                                                W1p, W2f, HWf, SWf, STWf, sp, cnt, perm);
    k_main<<<18 * REG_BLOCKS, 512, 0, stream>>>(x, perm, cnt,
                                                W1p, W2f, HWf, SWf, STWf,
                                                tb1, tb2, hb1, hw2, hb2,
                                                sb1, sw2, sb2, stb1, stw2, stb2,
                                                sp, sun_b1, sun_b2, storm_b1, storm_b2,
                                                (float*)d_out);
}